// Round 4
// baseline (62.597 us; speedup 1.0000x reference)
//
#include <hip/hip_runtime.h>
#include <math.h>

typedef float f4 __attribute__((ext_vector_type(4)));

constexpr int N_ELEM = 4096;        // row length (fixed for this problem)
constexpr int ROWS_PER_BLOCK = 8;   // 8192 rows / 1024 blocks

// p = sigmoid(x); lp = log p; l01 = log p + log(1-p).
// With u = 1 + e^{-|x|}, L = log u:
//   lp  = min(x,0) - L
//   l01 = -|x| - 2L
__device__ __forceinline__ void sig_terms(float x, float& p, float& lp, float& l01) {
    float ax = fabsf(x);
    float e  = __expf(-ax);
    float u  = 1.0f + e;
    float L  = __logf(u);
    float ru = __builtin_amdgcn_rcpf(u);
    p   = ((x >= 0.0f) ? 1.0f : e) * ru;
    lp  = fminf(x, 0.0f) - L;
    l01 = -ax - 2.0f * L;
}

__device__ __forceinline__ float sigmoid_only(float x) {
    float e  = __expf(-fabsf(x));
    float ru = __builtin_amdgcn_rcpf(1.0f + e);
    return ((x >= 0.0f) ? 1.0f : e) * ru;
}

// 1024 persistent blocks x 8 rows each. Within a row: wave w owns the
// contiguous 1024-elem segment [w*1024, (w+1)*1024); lane l, chunk c owns
// float4 at seg + 256c + 4l (lane-contiguous -> fully coalesced).
// Neighbors via in-wave shuffles; each wave scales its own segment partial
// by -t[row], so only ONE block reduction at the very end.
__global__ __launch_bounds__(256) void row_loss_kernel(
        const float* __restrict__ in,
        const float* __restrict__ tgt,
        float* __restrict__ block_out,
        float invN) {
    const int t = threadIdx.x;
    const int w = t >> 6;          // wave 0..3
    const int l = t & 63;          // lane
    const int seg = w << 10;       // 1024-elem segment start
    const int row0 = blockIdx.x * ROWS_PER_BLOCK;

    float total = 0.0f;

#pragma unroll 2
    for (int r = 0; r < ROWS_PER_BLOCK; ++r) {
        const int b = row0 + r;
        const float* __restrict__ row = in + (size_t)b * N_ELEM;

        // Wave-uniform boundary p values (zero padding at row ends).
        float pl_wave = (seg > 0)             ? sigmoid_only(row[seg - 1])    : 0.0f;
        float pr_wave = (seg + 1024 < N_ELEM) ? sigmoid_only(row[seg + 1024]) : 0.0f;

        float accH = 0.0f;   // sum p*(p_left+p_right)*logp over segment
        float accL = 0.0f;   // sum (logp + log(1-p)) over segment
        float prev_p3 = 0.0f;
        float dc = 0.0f;     // lane-63 deferred coefficient p3*lp3

#pragma unroll
        for (int c = 0; c < 4; ++c) {
            const int idx = seg + (c << 8) + (l << 2);
            f4 v = __builtin_nontemporal_load(
                       reinterpret_cast<const f4*>(row + idx));

            float p0, p1, p2, p3, lp0, lp1, lp2, lp3, q;
            sig_terms(v.x, p0, lp0, q); accL += q;
            sig_terms(v.y, p1, lp1, q); accL += q;
            sig_terms(v.z, p2, lp2, q); accL += q;
            sig_terms(v.w, p3, lp3, q); accL += q;

            // Resolve previous chunk's lane-63 deferred right-neighbor term.
            float b0 = __shfl(p0, 0);
            accH += dc * b0;

            float leftP  = __shfl_up(p3, 1);     // lane l-1's p3 = p[idx-1]
            float rightP = __shfl_down(p0, 1);   // lane l+1's p0 = p[idx+4]
            if (l == 0)  leftP  = (c == 0) ? pl_wave : __shfl(prev_p3, 63);
            if (l == 63) rightP = 0.0f;          // deferred below

            accH += p0 * (leftP + p1) * lp0;
            accH += p1 * (p0 + p2)    * lp1;
            accH += p2 * (p1 + p3)    * lp2;
            accH += p3 * (p2 + rightP)* lp3;

            dc = (l == 63) ? p3 * lp3 : 0.0f;
            prev_p3 = p3;
        }
        accH += dc * pr_wave;   // last chunk lane-63 right neighbor

        total = fmaf(-tgt[b], accH + invN * accL, total);
    }

    // One block reduction at the end: wave shuffle, then 4-value LDS combine.
#pragma unroll
    for (int off = 32; off > 0; off >>= 1) total += __shfl_down(total, off);

    __shared__ float sm[4];
    if (l == 0) sm[w] = total;
    __syncthreads();
    if (t == 0) block_out[blockIdx.x] = (sm[0] + sm[1]) + (sm[2] + sm[3]);
}

// Mean over block partials -> scalar. npart = B / ROWS_PER_BLOCK.
__global__ __launch_bounds__(256) void reduce_mean_kernel(
        const float* __restrict__ part, float* __restrict__ out,
        int npart, float invB) {
    const int nvec = npart >> 2;
    float acc = 0.0f;
    for (int i = threadIdx.x; i < nvec; i += 256) {
        f4 v = reinterpret_cast<const f4*>(part)[i];
        acc += (v.x + v.y) + (v.z + v.w);
    }
#pragma unroll
    for (int off = 32; off > 0; off >>= 1) acc += __shfl_down(acc, off);
    __shared__ float sm[4];
    if ((threadIdx.x & 63) == 0) sm[threadIdx.x >> 6] = acc;
    __syncthreads();
    if (threadIdx.x == 0) out[0] = ((sm[0] + sm[1]) + (sm[2] + sm[3])) * invB;
}

extern "C" void kernel_launch(void* const* d_in, const int* in_sizes, int n_in,
                              void* d_out, int out_size, void* d_ws, size_t ws_size,
                              hipStream_t stream) {
    const float* inputs  = (const float*)d_in[0];
    const float* targets = (const float*)d_in[1];
    float* out = (float*)d_out;

    const int B = in_sizes[1];            // 8192
    const int nblk = B / ROWS_PER_BLOCK;  // 1024

    float* block_part = (float*)d_ws;     // nblk floats of scratch

    row_loss_kernel<<<nblk, 256, 0, stream>>>(
        inputs, targets, block_part, 1.0f / (float)N_ELEM);
    reduce_mean_kernel<<<1, 256, 0, stream>>>(
        block_part, out, nblk, 1.0f / (float)B);
}